// Round 15
// baseline (207.703 us; speedup 1.0000x reference)
//
#include <hip/hip_runtime.h>
#include <hip/hip_fp16.h>

#define NNODES 100000
#define NEG_SLOPE 0.2f
#define NBK 49          // coarse buckets of 2048 nodes (dst>>11)
#define BKSHIFT 11
#define BKMASK 2047
#define BCAP 35328      // be[] slots/bucket; mean 32768, ~14 sigma slack
#define B1 4096         // edges per bin block
#define SLSTRIDE 56     // 56 % 8 == 0: slices of bucket B share blockIdx%8 == B%8

typedef _Float16 f16x8 __attribute__((ext_vector_type(8)));
typedef float f32x4 __attribute__((ext_vector_type(4)));

// ---------------- init + W^T f16 pre-swizzle ----------------
// Wt layouts match the LDS tiles the gemm phases consume, so blocks stage W
// with plain float4 copies (round 14: every gemm block re-did 8192 scalar
// LDS writes converting W).

__global__ void k_init(const float* __restrict__ W1, const float* __restrict__ W2,
                       __half* __restrict__ Wt1, __half* __restrict__ Wt2,
                       int* __restrict__ gcur, int* __restrict__ offs, int N, int E) {
    int t = threadIdx.x, b = blockIdx.x;
    if (b == 0) {
        if (t < NBK) gcur[t] = t * BCAP;
        if (t == NBK) offs[N] = E;
    }
    char* w1b = (char*)Wt1;
    for (int i = b * 1024 + t; i < (b + 1) * 1024 && i < 8192; i += 256) {
        int k = i >> 6, c = i & 63;
        *(__half*)(w1b + c * 256 + ((2 * k) ^ ((c & 7) << 4))) = __float2half(W1[i]);
    }
    char* w2b = (char*)Wt2;
    for (int i = b * 512 + t; i < (b + 1) * 512 && i < 4096; i += 256) {
        int k = i >> 6, c = i & 63;
        *(__half*)(w2b + c * 128 + ((2 * k) ^ ((c & 7) << 4))) = __float2half(W2[i]);
    }
}

// ---------------- fused: bin (blocks 0..390) + GEMM1 (rest) ----------------

__global__ __launch_bounds__(256, 5) void k_gemm1b(
    const float* __restrict__ x, const __half* __restrict__ Wt1,
    const float* __restrict__ al, const float* __restrict__ ar,
    __half* __restrict__ h, float* __restrict__ el, float* __restrict__ er,
    int N, int nbBin,
    const int* __restrict__ src, const int* __restrict__ dst,
    int* __restrict__ gcur, int* __restrict__ be, int E) {

    __shared__ float4 SMEM[2048];   // 32KB (gemm tiles)
    __shared__ int lcnt[NBK], lbase[NBK], lcur[NBK];
    int t = threadIdx.x;

    if ((int)blockIdx.x < nbBin) {  // ---- bin role ----
        int base = (int)blockIdx.x * B1;
        if (t < NBK) lcnt[t] = 0;
        __syncthreads();
        int dreg[16];
#pragma unroll
        for (int j = 0; j < 16; ++j) {
            int e = base + j * 256 + t;
            dreg[j] = (e < E) ? dst[e] : -1;
            if (e < E) atomicAdd(&lcnt[dreg[j] >> BKSHIFT], 1);
        }
        __syncthreads();
        if (t < NBK) { lbase[t] = atomicAdd(&gcur[t], lcnt[t]); lcur[t] = 0; }
        __syncthreads();
#pragma unroll
        for (int j = 0; j < 16; ++j) {
            int e = base + j * 256 + t;
            if (e < E) {
                int d = dreg[j];
                int bk = d >> BKSHIFT;
                int p = lbase[bk] + atomicAdd(&lcur[bk], 1);
                be[p] = (src[e] << BKSHIFT) | (d & BKMASK);
            }
        }
        return;
    }

    // ---- GEMM role ----
    char* A  = (char*)SMEM;          // 16KB: 64 rows x 256B f16 swz
    char* Bw = (char*)SMEM + 16384;  // 16KB: 64 cols x 256B f16 swz
    int row0 = ((int)blockIdx.x - nbBin) * 64;

    for (int i = t; i < 2048; i += 256) {
        int r = i >> 5, c4 = i & 31;
        int rr = row0 + r; if (rr > N - 1) rr = N - 1;
        float4 v = *(const float4*)(x + (size_t)rr * 128 + c4 * 4);
        int byte = r * 256 + ((c4 * 8) ^ ((r & 7) << 4));
        *(__half2*)(A + byte)     = __floats2half2_rn(v.x, v.y);
        *(__half2*)(A + byte + 4) = __floats2half2_rn(v.z, v.w);
    }
    for (int i = t; i < 1024; i += 256)
        ((float4*)Bw)[i] = ((const float4*)Wt1)[i];
    __syncthreads();

    int w = t >> 6, l = t & 63, g = l >> 4, c = l & 15;
    int swz = (c & 7) << 4;
    const char* Ar = A + (w * 16 + c) * 256;

    f32x4 acc[4];
#pragma unroll
    for (int t2 = 0; t2 < 4; ++t2) acc[t2] = (f32x4){0.f, 0.f, 0.f, 0.f};
#pragma unroll
    for (int kk = 0; kk < 4; ++kk) {
        int kb = kk * 64 + g * 16;
        f16x8 av = *(const f16x8*)(Ar + (kb ^ swz));
#pragma unroll
        for (int t2 = 0; t2 < 4; ++t2) {
            f16x8 bv = *(const f16x8*)(Bw + (t2 * 16 + c) * 256 + (kb ^ swz));
            acc[t2] = __builtin_amdgcn_mfma_f32_16x16x32_f16(av, bv, acc[t2], 0, 0, 0);
        }
    }

    float alv[4], arv[4];
#pragma unroll
    for (int t2 = 0; t2 < 4; ++t2) { alv[t2] = al[t2 * 16 + c]; arv[t2] = ar[t2 * 16 + c]; }
#pragma unroll
    for (int r = 0; r < 4; ++r) {
        float e1 = 0.f, e2 = 0.f;
#pragma unroll
        for (int t2 = 0; t2 < 4; ++t2) {
            e1 = fmaf(acc[t2][r], alv[t2], e1);
            e2 = fmaf(acc[t2][r], arv[t2], e2);
        }
#pragma unroll
        for (int o = 1; o < 16; o <<= 1) { e1 += __shfl_xor(e1, o); e2 += __shfl_xor(e2, o); }
        int row = row0 + w * 16 + 4 * g + r;
        if (row < N) {
            if (c == 0) { el[row] = e1; er[row] = e2; }
#pragma unroll
            for (int t2 = 0; t2 < 4; ++t2)
                h[(size_t)row * 64 + t2 * 16 + c] = __float2half(acc[t2][r]);
        }
    }
}

// ---------------- offs: per-bucket node histogram + scan -> offs[] ----------

__global__ __launch_bounds__(256) void k_offs(const int* __restrict__ be,
                                              const int* __restrict__ gcur,
                                              int* __restrict__ offs, int N) {
    __shared__ int cnt[2048];
    __shared__ int sb[2][256];
    __shared__ int rbeg;
    int B = blockIdx.x, t = threadIdx.x;
    int mycnt = gcur[B] - B * BCAP;
    int ebase = B * BCAP;

    for (int i = t; i < 2048; i += 256) cnt[i] = 0;
    if (t == 0) rbeg = 0;
    __syncthreads();
    for (int i = t; i < mycnt; i += 256) atomicAdd(&cnt[be[ebase + i] & BKMASK], 1);
    if (t < 64) {
        int v = (t < B) ? gcur[t] - t * BCAP : 0;
#pragma unroll
        for (int o = 32; o; o >>= 1) v += __shfl_xor(v, o);
        if (t == 0) rbeg = v;
    }
    __syncthreads();

    int loc[8], s = 0;
#pragma unroll
    for (int i = 0; i < 8; ++i) { loc[i] = s; s += cnt[8 * t + i]; }
    sb[0][t] = s;
    __syncthreads();
    int pi = 0;
    for (int d = 1; d < 256; d <<= 1) {
        int po = pi ^ 1;
        sb[po][t] = sb[pi][t] + (t >= d ? sb[pi][t - d] : 0);
        pi = po;
        __syncthreads();
    }
    int bas = rbeg + sb[pi][t] - s;

    int node0 = (B << BKSHIFT) + 8 * t;
#pragma unroll
    for (int i = 0; i < 8; ++i) {
        int node = node0 + i;
        if (node < N) offs[node] = bas + loc[i];
    }
}

// ---------------- scatter slices with XCD affinity ----------------

__global__ __launch_bounds__(256) void k_scat(const int* __restrict__ be,
                                              const int* __restrict__ gcur,
                                              const int* __restrict__ offs,
                                              int* __restrict__ csr, int N) {
    int b = blockIdx.x;
    int B = b % SLSTRIDE, sl = b / SLSTRIDE;
    if (B >= NBK) return;

    __shared__ int cur[256];
    int t = threadIdx.x;
    int mycnt = gcur[B] - B * BCAP;
    int ebase = B * BCAP;
    int node = (B << BKSHIFT) + sl * 256 + t;
    cur[t] = (node < N) ? offs[node] : 0;
    __syncthreads();
    for (int i = t; i < mycnt; i += 256) {
        int v = be[ebase + i];
        int loc = v & BKMASK;
        if ((loc >> 8) == sl) {
            int p = atomicAdd(&cur[loc & 255], 1);
            csr[p] = v >> BKSHIFT;
        }
    }
}

// ---------------- agg cores ----------------

__device__ inline float2 h2_to_f2(float bits) {
    return __half22float2(__builtin_bit_cast(__half2, bits));
}

__device__ inline void edge_one(float2 r0, float w0, float4& accv) {
    float2 f00 = h2_to_f2(r0.x), f01 = h2_to_f2(r0.y);
    accv.x = fmaf(w0, f00.x, accv.x); accv.y = fmaf(w0, f00.y, accv.y);
    accv.z = fmaf(w0, f01.x, accv.z); accv.w = fmaf(w0, f01.y, accv.w);
}

// scalar fallback (deg>64 path; ~never taken for Poisson(16))
__device__ float4 agg_node(const __half* __restrict__ h,
                           const float* __restrict__ el, float ern,
                           const int* __restrict__ csr_src,
                           int beg, int deg, int lane, int g, size_t foff) {
    float4 accv = make_float4(0.f, 0.f, 0.f, 0.f);
    int end = beg + deg;
    float m = -1e30f;
    for (int i = beg + lane; i < end; i += 64) {
        float e = el[csr_src[i]] + ern;
        e = e > 0.f ? e : NEG_SLOPE * e;
        m = fmaxf(m, e);
    }
#pragma unroll
    for (int o = 32; o; o >>= 1) m = fmaxf(m, __shfl_xor(m, o));
    float s = 0.f;
    for (int i = beg + lane; i < end; i += 64) {
        float e = el[csr_src[i]] + ern;
        e = e > 0.f ? e : NEG_SLOPE * e;
        s += __expf(e - m);
    }
#pragma unroll
    for (int o = 32; o; o >>= 1) s += __shfl_xor(s, o);
    float inv = 1.f / fmaxf(s, 1e-9f);
    for (int i = g; i < deg; i += 4) {
        int s0 = csr_src[beg + i];
        float e = el[s0] + ern;
        e = e > 0.f ? e : NEG_SLOPE * e;
        float w0 = __expf(e - m) * inv;
        float2 r0 = *(const float2*)(h + (size_t)s0 * 64 + foff);
        edge_one(r0, w0, accv);
    }
#pragma unroll
    for (int o = 16; o <= 32; o <<= 1) {
        accv.x += __shfl_xor(accv.x, o);
        accv.y += __shfl_xor(accv.y, o);
        accv.z += __shfl_xor(accv.z, o);
        accv.w += __shfl_xor(accv.w, o);
    }
    return accv;
}

// TWO nodes per wave: dual softmax + interleaved gather -> 8 lines in flight
// per lane (round 14: 4-deep MLP was the latency-bound limit; occupancy was
// grid-capped so more per-lane parallelism is the only lever). Lanes >= deg
// hold alpha=0/sidx=0 so padded iterations contribute exactly 0 (hot h[0]
// line). All shuffle trip counts wave-uniform (round-3 rule).
__device__ void agg_node2(const __half* __restrict__ h,
                          const float* __restrict__ el,
                          float ernA, float ernB,
                          const int* __restrict__ csr_src,
                          int begA, int degA, int begB, int degB,
                          int lane, int g, size_t foff,
                          float4& accA, float4& accB) {
    accA = make_float4(0.f, 0.f, 0.f, 0.f);
    accB = make_float4(0.f, 0.f, 0.f, 0.f);

    if (degA > 64 || degB > 64) {   // wave-uniform branch; ~never
        accA = agg_node(h, el, ernA, csr_src, begA, degA, lane, g, foff);
        accB = agg_node(h, el, ernB, csr_src, begB, degB, lane, g, foff);
        return;
    }

    int sA = 0, sB = 0;
    float eA = -1e30f, eB = -1e30f;
    if (lane < degA) {
        sA = csr_src[begA + lane];
        float v = el[sA] + ernA;
        eA = v > 0.f ? v : NEG_SLOPE * v;
    }
    if (lane < degB) {
        sB = csr_src[begB + lane];
        float v = el[sB] + ernB;
        eB = v > 0.f ? v : NEG_SLOPE * v;
    }
    float mA = eA, mB = eB;
#pragma unroll
    for (int o = 32; o; o >>= 1) {
        mA = fmaxf(mA, __shfl_xor(mA, o));
        mB = fmaxf(mB, __shfl_xor(mB, o));
    }
    float pA = (lane < degA) ? __expf(eA - mA) : 0.f;
    float pB = (lane < degB) ? __expf(eB - mB) : 0.f;
    float uA = pA, uB = pB;
#pragma unroll
    for (int o = 32; o; o >>= 1) {
        uA += __shfl_xor(uA, o);
        uB += __shfl_xor(uB, o);
    }
    float aA = pA * (1.f / fmaxf(uA, 1e-9f));
    float aB = pB * (1.f / fmaxf(uB, 1e-9f));

    int nqA = (degA + 3) >> 2, nqB = (degB + 3) >> 2;
    int nq = nqA > nqB ? nqA : nqB;   // wave-uniform
    int oct = nq >> 2, rem = nq & 3;
    int i = g;
    for (int t4 = 0; t4 < oct; ++t4, i += 16) {
        int a0 = __shfl(sA, i),      a1 = __shfl(sA, i + 4);
        int a2 = __shfl(sA, i + 8),  a3 = __shfl(sA, i + 12);
        int b0 = __shfl(sB, i),      b1 = __shfl(sB, i + 4);
        int b2 = __shfl(sB, i + 8),  b3 = __shfl(sB, i + 12);
        float wa0 = __shfl(aA, i),     wa1 = __shfl(aA, i + 4);
        float wa2 = __shfl(aA, i + 8), wa3 = __shfl(aA, i + 12);
        float wb0 = __shfl(aB, i),     wb1 = __shfl(aB, i + 4);
        float wb2 = __shfl(aB, i + 8), wb3 = __shfl(aB, i + 12);
        float2 ra0 = *(const float2*)(h + (size_t)a0 * 64 + foff);
        float2 ra1 = *(const float2*)(h + (size_t)a1 * 64 + foff);
        float2 ra2 = *(const float2*)(h + (size_t)a2 * 64 + foff);
        float2 ra3 = *(const float2*)(h + (size_t)a3 * 64 + foff);
        float2 rb0 = *(const float2*)(h + (size_t)b0 * 64 + foff);
        float2 rb1 = *(const float2*)(h + (size_t)b1 * 64 + foff);
        float2 rb2 = *(const float2*)(h + (size_t)b2 * 64 + foff);
        float2 rb3 = *(const float2*)(h + (size_t)b3 * 64 + foff);
        edge_one(ra0, wa0, accA); edge_one(ra1, wa1, accA);
        edge_one(ra2, wa2, accA); edge_one(ra3, wa3, accA);
        edge_one(rb0, wb0, accB); edge_one(rb1, wb1, accB);
        edge_one(rb2, wb2, accB); edge_one(rb3, wb3, accB);
    }
    for (; rem > 0; --rem, i += 4) {
        int a0 = __shfl(sA, i), b0 = __shfl(sB, i);
        float wa0 = __shfl(aA, i), wb0 = __shfl(aB, i);
        float2 ra0 = *(const float2*)(h + (size_t)a0 * 64 + foff);
        float2 rb0 = *(const float2*)(h + (size_t)b0 * 64 + foff);
        edge_one(ra0, wa0, accA);
        edge_one(rb0, wb0, accB);
    }

#pragma unroll
    for (int o = 16; o <= 32; o <<= 1) {
        accA.x += __shfl_xor(accA.x, o); accA.y += __shfl_xor(accA.y, o);
        accA.z += __shfl_xor(accA.z, o); accA.w += __shfl_xor(accA.w, o);
        accB.x += __shfl_xor(accB.x, o); accB.y += __shfl_xor(accB.y, o);
        accB.z += __shfl_xor(accB.z, o); accB.w += __shfl_xor(accB.w, o);
    }
}

// ---------------- fused agg1 + GEMM2 ----------------

__global__ __launch_bounds__(256, 6) void k_aggemm(
    const __half* __restrict__ h, const float* __restrict__ el,
    const float* __restrict__ er, const float* __restrict__ b1,
    const int* __restrict__ offs, const int* __restrict__ csr_src,
    const __half* __restrict__ Wt2, const float* __restrict__ al2,
    const float* __restrict__ ar2,
    __half* __restrict__ h2, float* __restrict__ el2, float* __restrict__ er2,
    int N) {

    __shared__ float4 SMEM[1024];    // 16KB: A 8KB | W2t 8KB
    char* A  = (char*)SMEM;
    char* Bw = (char*)SMEM + 8192;
    int t = threadIdx.x;
    int w = t >> 6, lane = t & 63, g = lane >> 4, fl = lane & 15;
    int row0 = blockIdx.x * 64;

    for (int i = t; i < 512; i += 256)
        ((float4*)Bw)[i] = ((const float4*)Wt2)[i];

    // ---- agg phase: wave w handles rows w*16 .. w*16+15, two at a time ----
    const size_t foff = 4 * (size_t)fl;
    float4 bv = *(const float4*)(b1 + foff);   // used by lanes 0..15
    for (int j = 0; j < 16; j += 2) {
        int rA = w * 16 + j;
        int nA = row0 + rA, nB = nA + 1;
        int begA = 0, degA = 0, begB = 0, degB = 0;
        float ernA = 0.f, ernB = 0.f;
        if (nA < N) { begA = offs[nA]; degA = offs[nA + 1] - begA; ernA = er[nA]; }
        if (nB < N) { begB = offs[nB]; degB = offs[nB + 1] - begB; ernB = er[nB]; }
        float4 accA, accB;
        agg_node2(h, el, ernA, ernB, csr_src, begA, degA, begB, degB,
                  lane, g, foff, accA, accB);
        if (lane < 16) {
            float ox = fmaxf(accA.x + bv.x, 0.f);
            float oy = fmaxf(accA.y + bv.y, 0.f);
            float oz = fmaxf(accA.z + bv.z, 0.f);
            float ow = fmaxf(accA.w + bv.w, 0.f);
            float2 pk;
            pk.x = __builtin_bit_cast(float, __floats2half2_rn(ox, oy));
            pk.y = __builtin_bit_cast(float, __floats2half2_rn(oz, ow));
            *(float2*)(A + rA * 128 + ((int)(fl * 8) ^ ((rA & 7) << 4))) = pk;
            int rB = rA + 1;
            ox = fmaxf(accB.x + bv.x, 0.f);
            oy = fmaxf(accB.y + bv.y, 0.f);
            oz = fmaxf(accB.z + bv.z, 0.f);
            ow = fmaxf(accB.w + bv.w, 0.f);
            pk.x = __builtin_bit_cast(float, __floats2half2_rn(ox, oy));
            pk.y = __builtin_bit_cast(float, __floats2half2_rn(oz, ow));
            *(float2*)(A + rB * 128 + ((int)(fl * 8) ^ ((rB & 7) << 4))) = pk;
        }
    }
    __syncthreads();

    // ---- MFMA phase (gemm2) ----
    int c = fl;
    int swz = (c & 7) << 4;
    const char* Ar = A + (w * 16 + c) * 128;

    f32x4 acc[4];
#pragma unroll
    for (int t2 = 0; t2 < 4; ++t2) acc[t2] = (f32x4){0.f, 0.f, 0.f, 0.f};
#pragma unroll
    for (int kk = 0; kk < 2; ++kk) {
        int kb = kk * 64 + g * 16;
        f16x8 av = *(const f16x8*)(Ar + (kb ^ swz));
#pragma unroll
        for (int t2 = 0; t2 < 4; ++t2) {
            f16x8 bvf = *(const f16x8*)(Bw + (t2 * 16 + c) * 128 + (kb ^ swz));
            acc[t2] = __builtin_amdgcn_mfma_f32_16x16x32_f16(av, bvf, acc[t2], 0, 0, 0);
        }
    }

    float alv[4], arv[4];
#pragma unroll
    for (int t2 = 0; t2 < 4; ++t2) { alv[t2] = al2[t2 * 16 + c]; arv[t2] = ar2[t2 * 16 + c]; }
#pragma unroll
    for (int r = 0; r < 4; ++r) {
        float e1 = 0.f, e2 = 0.f;
#pragma unroll
        for (int t2 = 0; t2 < 4; ++t2) {
            e1 = fmaf(acc[t2][r], alv[t2], e1);
            e2 = fmaf(acc[t2][r], arv[t2], e2);
        }
#pragma unroll
        for (int o = 1; o < 16; o <<= 1) { e1 += __shfl_xor(e1, o); e2 += __shfl_xor(e2, o); }
        int row = row0 + w * 16 + 4 * g + r;
        if (row < N) {
            if (c == 0) { el2[row] = e1; er2[row] = e2; }
#pragma unroll
            for (int t2 = 0; t2 < 4; ++t2)
                h2[(size_t)row * 64 + t2 * 16 + c] = __float2half(acc[t2][r]);
        }
    }
}

// ---------------- layer-2 agg (writes fp32 out), two nodes per wave --------

__global__ __launch_bounds__(256, 6) void k_agg2(const __half* __restrict__ h,
                                                 const float* __restrict__ el,
                                                 const float* __restrict__ er,
                                                 const float* __restrict__ b,
                                                 const int* __restrict__ offs,
                                                 const int* __restrict__ csr_src,
                                                 float* __restrict__ out, int N) {
    int wave = threadIdx.x >> 6, lane = threadIdx.x & 63;
    int nA = blockIdx.x * 8 + wave * 2;
    if (nA >= N) return;
    int nB = nA + 1;

    int g = lane >> 4, fl = lane & 15;
    const size_t foff = 4 * (size_t)fl;

    int begA = offs[nA], degA = offs[nA + 1] - begA;
    float ernA = er[nA];
    int begB = 0, degB = 0;
    float ernB = 0.f;
    if (nB < N) { begB = offs[nB]; degB = offs[nB + 1] - begB; ernB = er[nB]; }

    float4 accA, accB;
    agg_node2(h, el, ernA, ernB, csr_src, begA, degA, begB, degB,
              lane, g, foff, accA, accB);

    if (lane < 16) {
        float4 bv = *(const float4*)(b + foff);
        *(float4*)(out + (size_t)nA * 64 + foff) =
            make_float4(accA.x + bv.x, accA.y + bv.y, accA.z + bv.z, accA.w + bv.w);
        if (nB < N)
            *(float4*)(out + (size_t)nB * 64 + foff) =
                make_float4(accB.x + bv.x, accB.y + bv.y, accB.z + bv.z, accB.w + bv.w);
    }
}

// ---------------- launch ----------------

extern "C" void kernel_launch(void* const* d_in, const int* in_sizes, int n_in,
                              void* d_out, int out_size, void* d_ws, size_t ws_size,
                              hipStream_t stream) {
    const float* x   = (const float*)d_in[0];
    const int*   src = (const int*)d_in[1];
    const int*   dst = (const int*)d_in[2];
    const float* W1  = (const float*)d_in[3];
    const float* al1 = (const float*)d_in[4];
    const float* ar1 = (const float*)d_in[5];
    const float* b1  = (const float*)d_in[6];
    const float* W2  = (const float*)d_in[7];
    const float* al2 = (const float*)d_in[8];
    const float* ar2 = (const float*)d_in[9];
    const float* b2  = (const float*)d_in[10];
    float* out = (float*)d_out;

    const int N = NNODES;
    const int E = in_sizes[1];

    __half* h    = (__half*)d_ws;                      // 12.8MB (layer-1 h)
    __half* h2   = h + (size_t)N * 64;                 // 12.8MB (layer-2 h)
    int*    be   = (int*)(h2 + (size_t)N * 64);        // NBK*BCAP (6.9MB)
    int*    csr  = be + (size_t)NBK * BCAP;            // E (6.4MB)
    float*  el   = (float*)(csr + E);                  // N
    float*  er   = el + N;                             // N
    float*  el2  = er + N;                             // N
    float*  er2  = el2 + N;                            // N
    int*    offs = (int*)(er2 + N);                    // N+1
    int*    gcur = offs + N + 1;                       // NBK
    __half* Wt1  = (__half*)(gcur + NBK + 15);         // 8192 halfs (16KB)
    __half* Wt2  = Wt1 + 8192;                         // 4096 halfs (8KB)

    int nbBin = (E + B1 - 1) / B1;            // 391
    int nbG   = (N + 63) / 64;                // 1563
    int nbR2  = (N + 7) / 8;                  // 12500

    k_init<<<8, 256, 0, stream>>>(W1, W2, Wt1, Wt2, gcur, offs, N, E);
    // bin (391 blocks) fused with layer-1 MFMA GEMM (1563 blocks) - independent
    k_gemm1b<<<nbBin + nbG, 256, 0, stream>>>(x, Wt1, al1, ar1, h, el, er, N,
                                              nbBin, src, dst, gcur, be, E);
    k_offs<<<NBK, 256, 0, stream>>>(be, gcur, offs, N);
    k_scat<<<8 * SLSTRIDE, 256, 0, stream>>>(be, gcur, offs, csr, N);
    // fused: agg layer-1 + GEMM2 (hmid stays in LDS)
    k_aggemm<<<nbG, 256, 0, stream>>>(h, el, er, b1, offs, csr,
                                      Wt2, al2, ar2, h2, el2, er2, N);
    k_agg2<<<nbR2, 256, 0, stream>>>(h2, el2, er2, b2, offs, csr, out, N);
}